// Round 13
// baseline (139.930 us; speedup 1.0000x reference)
//
#include <hip/hip_runtime.h>
#include <cstdint>

typedef unsigned uint;
typedef unsigned short u16;
typedef int v4i  __attribute__((ext_vector_type(4)));
typedef int v16i __attribute__((ext_vector_type(16)));
typedef float v2f __attribute__((ext_vector_type(2)));

// d_ws word layout:
//   [0,144)       w1 signs as +-1.0f
//   [144,1424)    W2B: conv2 weight frags, f=s*64+l: oc=l&31, tap=2s+(l>>5), ic=e
//   [1424,3728)   W3B: conv3 weight frags, f=s*64+l: oc=l&31, tap=s, ic=(l>>5)*16+e
//   [3728,8568)   wfc packed to 22x22 grid, PERMUTED bit order (see bitpos)
static constexpr int WS_W2B = 144;
static constexpr int WS_W3B = 1424;
static constexpr int WS_FC  = 3728;

// LDS layout, 20.9KB -> 7 blocks/CU (same as R11/R12).
static constexpr int L_XS  = 0;
static constexpr int L_H1  = 3136;
static constexpr int L_H2  = 0;
static constexpr int L_H2B = 18432;
static constexpr int L_H3  = 18432;
static constexpr int L_RED = 20736;  // uint[4][5]
static constexpr int L_LG  = 20816;  // float[10]
static constexpr int L_TOT = 20856;

// Permuted bit position for channel c in h2w/h3 words:
// lane-half h = c[2], reg r = (c&3) + 4*(c>>3); bitpos = 16h + r.
__device__ __host__ __forceinline__ int bitpos32(int c) {
    return (((c >> 2) & 1) << 4) + (c & 3) + ((c >> 3) << 2);
}

__global__ __launch_bounds__(256) void pack_kernel(
    const float* __restrict__ w1, const float* __restrict__ w2,
    const float* __restrict__ w3, const float* __restrict__ wfc,
    uint* __restrict__ wsu)
{
    int gid = blockIdx.x * 256 + threadIdx.x;
    if (gid < 144) {
        ((float*)wsu)[gid] = (w1[gid] >= 0.f) ? 1.f : -1.f;
    } else if (gid < 464) {
        // conv2 weight frag (A-operand): oc = l&31, tap = 2s+(l>>5), ic = e
        int f = gid - 144, s = f >> 6, l = f & 63;
        int oc = l & 31, tap = s * 2 + (l >> 5);
        uint w[4] = {0u, 0u, 0u, 0u};
        if (tap < 9) {
            for (int e = 0; e < 16; ++e) {
                uint b = (w2[(oc * 16 + e) * 9 + tap] >= 0.f) ? 0x01u : 0xFFu;
                w[e >> 2] |= b << (8 * (e & 3));
            }
        }
        for (int j = 0; j < 4; ++j) wsu[WS_W2B + f * 4 + j] = w[j];
    } else if (gid < 1040) {
        // conv3 weight frag (A-operand): oc = l&31, tap = s, ic = (l>>5)*16+e
        int f = gid - 464, s = f >> 6, l = f & 63;
        int oc = l & 31, icb = (l >> 5) * 16;
        uint w[4] = {0u, 0u, 0u, 0u};
        for (int e = 0; e < 16; ++e) {
            uint b = (w3[(oc * 32 + icb + e) * 9 + s] >= 0.f) ? 0x01u : 0xFFu;
            w[e >> 2] |= b << (8 * (e & 3));
        }
        for (int j = 0; j < 4; ++j) wsu[WS_W3B + f * 4 + j] = w[j];
    } else if (gid < 5880) {
        // FC weights, bit order matching conv3's per-lane mask build.
        int f = gid - 1040, o = f / 484, p = f % 484;
        int Y = p / 22, X = p % 22;
        const float* base = wfc + o * 3872 + (Y >> 1) * 11 + (X >> 1);
        uint bits = 0;
        for (int c = 0; c < 32; ++c)
            bits |= (base[c * 121] >= 0.f ? 1u : 0u) << bitpos32(c);
        wsu[WS_FC + f] = bits;
    }
}

// 4 sign bits -> 4 i8 bytes (bit=1 -> +1, bit=0 -> -1)
__device__ __forceinline__ int expand4(uint t) {
    return (int)~(((t * 0x00204081u) & 0x01010101u) * 0xFEu);
}
__device__ __forceinline__ v4i expand16(uint bits) {
    v4i r;
    r[0] = expand4(bits & 0xFu);
    r[1] = expand4((bits >> 4) & 0xFu);
    r[2] = expand4((bits >> 8) & 0xFu);
    r[3] = expand4((bits >> 12) & 0xFu);
    return r;
}

__global__ __launch_bounds__(256) void binet_kernel(
    const float* __restrict__ x, const uint* __restrict__ wsu,
    const float* __restrict__ bfc, float* __restrict__ out)
{
    __shared__ __align__(16) unsigned char lds[L_TOT];
    const int t = threadIdx.x;
    const int img = blockIdx.x;
    const int l = t & 63, wave = t >> 6, half = l >> 5, lane31 = l & 31;

    float* xs = (float*)(lds + L_XS);
    signed char* h1 = (signed char*)(lds + L_H1);
    signed char* h2 = (signed char*)(lds + L_H2);
    u16*  h2u = (u16*)(lds + L_H2B);
    uint* h2w = (uint*)(lds + L_H2B);
    u16*  h3u = (u16*)(lds + L_H3);
    uint* h3  = (uint*)(lds + L_H3);
    uint (*red)[5] = (uint(*)[5])(lds + L_RED);
    float* lg = (float*)(lds + L_LG);

    // ---- load image ----
    {
        const float* xin = x + (size_t)img * 784;
        for (int i = t; i < 784; i += 256) xs[i] = xin[i];
    }
    __syncthreads();

    // ---- conv1: 4 positions/thread, fully packed v_pk_fma; merged rare
    // fp64 fallback. Thread (g = t/26, xcol = t%26) owns rows 4g..4g+3
    // (g=6: rows 24,25), col xcol. 182 active threads.
    if (t < 182) {
        const float* wf = (const float*)wsu;   // uniform -> scalar loads
        const int g = t / 26, xcol = t - g * 26;
        const int y0 = 4 * g;
        // window rows y0..y0+5 (clamped), cols xcol..xcol+2, as pk pairs:
        // xpA[k] = (win[ky], win[ky+1]), xpB[k] = (win[ky+2], win[ky+3])
        v2f xpA[9], xpB[9];
        #pragma unroll
        for (int ky = 0; ky < 3; ++ky)
            #pragma unroll
            for (int kx = 0; kx < 3; ++kx) {
                int r0 = y0 + ky;
                int r1 = r0 + 1, r2 = r0 + 2, r3 = r0 + 3;
                if (r3 > 27) r3 = 27;
                if (r2 > 27) r2 = 27;
                v2f a, b;
                a.x = xs[r0*28 + xcol + kx];
                a.y = xs[r1*28 + xcol + kx];
                b.x = xs[r2*28 + xcol + kx];
                b.y = xs[r3*28 + xcol + kx];
                xpA[ky*3+kx] = a;
                xpB[ky*3+kx] = b;
            }
        uint m0 = 0, m1 = 0, m2 = 0, m3 = 0;
        for (int oc = 0; oc < 16; ++oc) {
            v2f s01 = {0.f, 0.f}, s23 = {0.f, 0.f};
            #pragma unroll
            for (int k = 0; k < 9; ++k) {
                float w = wf[oc*9 + k];
                s01 = xpA[k] * w + s01;   // v_pk_fma_f32
                s23 = xpB[k] * w + s23;
            }
            bool b0 = (s01.x >= 0.f), b1 = (s01.y >= 0.f);
            bool b2 = (s23.x >= 0.f), b3 = (s23.y >= 0.f);
            // fp32 accum error bound ~2.9e-5 << 1e-4: outside the band the
            // fp32 sign equals the exact (fp64) sign.
            float mx = fmaxf(fmaxf(fabsf(s01.x), fabsf(s01.y)),
                             fmaxf(fabsf(s23.x), fabsf(s23.y)));
            if (__builtin_expect(mx < 1e-4f, 0)) {
                double d0 = 0.0, d1 = 0.0, d2 = 0.0, d3 = 0.0;
                for (int k = 0; k < 9; ++k) {
                    double w = (double)wf[oc*9 + k];
                    d0 += (double)xpA[k].x * w;
                    d1 += (double)xpA[k].y * w;
                    d2 += (double)xpB[k].x * w;
                    d3 += (double)xpB[k].y * w;
                }
                b0 = (d0 >= 0.0); b1 = (d1 >= 0.0);
                b2 = (d2 >= 0.0); b3 = (d3 >= 0.0);
            }
            m0 |= (uint)b0 << oc;
            m1 |= (uint)b1 << oc;
            m2 |= (uint)b2 << oc;
            m3 |= (uint)b3 << oc;
        }
        *(v4i*)(h1 + ((y0    )*26 + xcol)*16) = expand16(m0);
        *(v4i*)(h1 + ((y0 + 1)*26 + xcol)*16) = expand16(m1);
        if (y0 + 2 < 26) {
            *(v4i*)(h1 + ((y0 + 2)*26 + xcol)*16) = expand16(m2);
            *(v4i*)(h1 + ((y0 + 3)*26 + xcol)*16) = expand16(m3);
        }
    }
    __syncthreads();

    // ---- conv2 via i8 MFMA, SWAPPED operands: D[oc][pos] ----
    {
        const v4i* w2bp = (const v4i*)(wsu + WS_W2B);
        v4i b2f[5];
        #pragma unroll
        for (int s = 0; s < 5; ++s) b2f[s] = w2bp[s*64 + l];
        for (int tile = wave; tile < 18; tile += 4) {
            const int mb = tile * 32;
            const int row = mb + lane31;
            const int y = row / 24, xx = row % 24;
            v16i acc = {0,0,0,0,0,0,0,0,0,0,0,0,0,0,0,0};
            #pragma unroll
            for (int s = 0; s < 5; ++s) {
                int tap = s*2 + half; if (tap > 8) tap = 8;  // W zeroed for tap 9
                int ky = tap / 3, kx = tap - ky*3;
                v4i b = *(const v4i*)(h1 + ((y+ky)*26 + xx+kx)*16);
                acc = __builtin_amdgcn_mfma_i32_32x32x32_i8(b2f[s], b, acc, 0, 0, 0);
            }
            uint mneg = 0;
            #pragma unroll
            for (int r = 0; r < 16; ++r)
                mneg |= (((uint)acc[r]) >> 31) << r;   // bit r = sign(oc(r,half))
            h2u[row*2 + half] = (u16)~mneg;
        }
    }
    __syncthreads();

    // ---- expand h2w -> h2 i8[2][576][16] (permuted-nibble unpack) ----
    for (int p = t; p < 576; p += 256) {
        uint w = h2w[p];
        v4i lo, hi;
        lo[0] = expand4( w        & 0xFu);
        lo[1] = expand4((w >> 16) & 0xFu);
        lo[2] = expand4((w >>  4) & 0xFu);
        lo[3] = expand4((w >> 20) & 0xFu);
        hi[0] = expand4((w >>  8) & 0xFu);
        hi[1] = expand4((w >> 24) & 0xFu);
        hi[2] = expand4((w >> 12) & 0xFu);
        hi[3] = expand4((w >> 28) & 0xFu);
        *(v4i*)(h2 + p*16)        = lo;   // ic 0-15
        *(v4i*)(h2 + 9216 + p*16) = hi;   // ic 16-31
    }
    __syncthreads();

    // ---- conv3 via i8 MFMA, SWAPPED operands: D[oc][pos] ----
    {
        const v4i* w3bp = (const v4i*)(wsu + WS_W3B);
        v4i b3f[9];
        #pragma unroll
        for (int s = 0; s < 9; ++s) b3f[s] = w3bp[s*64 + l];
        const signed char* h2h = h2 + half*9216;
        for (int tile = wave; tile < 16; tile += 4) {
            const int mb = tile * 32;
            int row = mb + lane31;
            int pr = (row < 484) ? row : 483;
            const int y = pr / 22, xx = pr % 22;
            v16i acc = {0,0,0,0,0,0,0,0,0,0,0,0,0,0,0,0};
            #pragma unroll
            for (int s = 0; s < 9; ++s) {
                const int ky = s / 3, kx = s - ky*3;
                v4i b = *(const v4i*)(h2h + ((y+ky)*24 + xx+kx)*16);
                acc = __builtin_amdgcn_mfma_i32_32x32x32_i8(b3f[s], b, acc, 0, 0, 0);
            }
            uint mneg = 0;
            #pragma unroll
            for (int r = 0; r < 16; ++r)
                mneg |= (((uint)acc[r]) >> 31) << r;
            if (row < 484) h3u[row*2 + half] = (u16)~mneg;
        }
    }
    __syncthreads();

    // ---- avgpool + FC as binary dot (permuted bits match wfc packing) ----
    uint acc5[5] = {0u, 0u, 0u, 0u, 0u};
    for (int p = t; p < 484; p += 256) {
        uint h = h3[p];
        const uint* wp = wsu + WS_FC + p;
        #pragma unroll
        for (int o = 0; o < 5; ++o)
            acc5[o] += (uint)__popc(h ^ wp[(2*o)*484])
                     + ((uint)__popc(h ^ wp[(2*o+1)*484]) << 16);
    }
    #pragma unroll
    for (int o = 0; o < 5; ++o) {
        uint v = acc5[o];
        v += __shfl_down(v, 32); v += __shfl_down(v, 16);
        v += __shfl_down(v, 8);  v += __shfl_down(v, 4);
        v += __shfl_down(v, 2);  v += __shfl_down(v, 1);
        acc5[o] = v;
    }
    if (l == 0) {
        #pragma unroll
        for (int o = 0; o < 5; ++o) red[wave][o] = acc5[o];
    }
    __syncthreads();
    if (t < 10) {
        uint S = 0;
        #pragma unroll
        for (int j = 0; j < 4; ++j) {
            uint w = red[j][t >> 1];
            S += (t & 1) ? (w >> 16) : (w & 0xFFFFu);
        }
        lg[t] = 0.25f * (float)(15488 - 2*(int)S) + bfc[t];
    }
    __syncthreads();
    if (t < 10) {
        float m = lg[0];
        #pragma unroll
        for (int o = 1; o < 10; ++o) m = fmaxf(m, lg[o]);
        float se = 0.f;
        #pragma unroll
        for (int o = 0; o < 10; ++o) se += expf(lg[o] - m);
        out[(size_t)img*10 + t] = lg[t] - m - logf(se);
    }
}

extern "C" void kernel_launch(void* const* d_in, const int* in_sizes, int n_in,
                              void* d_out, int out_size, void* d_ws, size_t ws_size,
                              hipStream_t stream)
{
    const float* x   = (const float*)d_in[0];
    const float* w1  = (const float*)d_in[1];
    const float* w2  = (const float*)d_in[2];
    const float* w3  = (const float*)d_in[3];
    const float* wfc = (const float*)d_in[4];
    const float* bfc = (const float*)d_in[5];
    float* out = (float*)d_out;
    uint* wsu  = (uint*)d_ws;

    const int B = in_sizes[0] / 784;   // 8192

    hipLaunchKernelGGL(pack_kernel, dim3(23), dim3(256), 0, stream,
                       w1, w2, w3, wfc, wsu);
    hipLaunchKernelGGL(binet_kernel, dim3(B), dim3(256), 0, stream,
                       x, wsu, bfc, out);
}

// Round 16
// 123.501 us; speedup vs baseline: 1.1330x; 1.1330x over previous
//
#include <hip/hip_runtime.h>
#include <cstdint>

typedef unsigned uint;
typedef unsigned short u16;
typedef int v4i  __attribute__((ext_vector_type(4)));
typedef int v16i __attribute__((ext_vector_type(16)));
typedef float v2f __attribute__((ext_vector_type(2)));

// d_ws word layout:
//   [0,144)       w1 signs as +-1.0f
//   [144,1424)    W2B: conv2 weight frags, f=s*64+l: oc=l&31, tap=2s+(l>>5), ic=e
//   [1424,3728)   W3B: conv3 weight frags, f=s*64+l: oc=l&31, tap=s, ic=(l>>5)*16+e
//   [3728,8568)   wfc packed to 22x22 grid, PERMUTED bit order (see bitpos)
static constexpr int WS_W2B = 144;
static constexpr int WS_W3B = 1424;
static constexpr int WS_FC  = 3728;

// LDS layout, 20368B -> rounds to 20480 -> EXACTLY 8 blocks/CU (32 waves, cap).
// Region A [0,18432):
//   conv1:  xs f32[784] [0,3136) + h1 i8[676][16] [3136,13952)
//   conv2:  reads h1; writes h2w u16[576][2] into gap [13952,16256)
//   expand: reads h2w (buffered to regs, barrier), writes h2 i8[2][576][16]
//           over [0,18432)
//   FC:     red uint[4][5] at [0,80), lg float[10] at [80,120) (A dead)
// Region B [18432,20368): h3 uint[484] (conv3 out / FC in)
static constexpr int L_XS  = 0;
static constexpr int L_H1  = 3136;
static constexpr int L_H2  = 0;
static constexpr int L_H2B = 13952;
static constexpr int L_H3  = 18432;
static constexpr int L_RED = 0;
static constexpr int L_LG  = 80;
static constexpr int L_TOT = 20368;

// Permuted bit position for channel c in h2w/h3 words:
// lane-half h = c[2], reg r = (c&3) + 4*(c>>3); bitpos = 16h + r.
__device__ __host__ __forceinline__ int bitpos32(int c) {
    return (((c >> 2) & 1) << 4) + (c & 3) + ((c >> 3) << 2);
}

__global__ __launch_bounds__(256) void pack_kernel(
    const float* __restrict__ w1, const float* __restrict__ w2,
    const float* __restrict__ w3, const float* __restrict__ wfc,
    uint* __restrict__ wsu)
{
    int gid = blockIdx.x * 256 + threadIdx.x;
    if (gid < 144) {
        ((float*)wsu)[gid] = (w1[gid] >= 0.f) ? 1.f : -1.f;
    } else if (gid < 464) {
        // conv2 weight frag (A-operand): oc = l&31, tap = 2s+(l>>5), ic = e
        int f = gid - 144, s = f >> 6, l = f & 63;
        int oc = l & 31, tap = s * 2 + (l >> 5);
        uint w[4] = {0u, 0u, 0u, 0u};
        if (tap < 9) {
            for (int e = 0; e < 16; ++e) {
                uint b = (w2[(oc * 16 + e) * 9 + tap] >= 0.f) ? 0x01u : 0xFFu;
                w[e >> 2] |= b << (8 * (e & 3));
            }
        }
        for (int j = 0; j < 4; ++j) wsu[WS_W2B + f * 4 + j] = w[j];
    } else if (gid < 1040) {
        // conv3 weight frag (A-operand): oc = l&31, tap = s, ic = (l>>5)*16+e
        int f = gid - 464, s = f >> 6, l = f & 63;
        int oc = l & 31, icb = (l >> 5) * 16;
        uint w[4] = {0u, 0u, 0u, 0u};
        for (int e = 0; e < 16; ++e) {
            uint b = (w3[(oc * 32 + icb + e) * 9 + s] >= 0.f) ? 0x01u : 0xFFu;
            w[e >> 2] |= b << (8 * (e & 3));
        }
        for (int j = 0; j < 4; ++j) wsu[WS_W3B + f * 4 + j] = w[j];
    } else if (gid < 5880) {
        // FC weights, bit order matching conv3's per-lane mask build.
        int f = gid - 1040, o = f / 484, p = f % 484;
        int Y = p / 22, X = p % 22;
        const float* base = wfc + o * 3872 + (Y >> 1) * 11 + (X >> 1);
        uint bits = 0;
        for (int c = 0; c < 32; ++c)
            bits |= (base[c * 121] >= 0.f ? 1u : 0u) << bitpos32(c);
        wsu[WS_FC + f] = bits;
    }
}

// 4 sign bits -> 4 i8 bytes (bit=1 -> +1, bit=0 -> -1)
__device__ __forceinline__ int expand4(uint t) {
    return (int)~(((t * 0x00204081u) & 0x01010101u) * 0xFEu);
}
__device__ __forceinline__ v4i expand16(uint bits) {
    v4i r;
    r[0] = expand4(bits & 0xFu);
    r[1] = expand4((bits >> 4) & 0xFu);
    r[2] = expand4((bits >> 8) & 0xFu);
    r[3] = expand4((bits >> 12) & 0xFu);
    return r;
}

__global__ __launch_bounds__(256) void binet_kernel(
    const float* __restrict__ x, const uint* __restrict__ wsu,
    const float* __restrict__ bfc, float* __restrict__ out)
{
    __shared__ __align__(16) unsigned char lds[L_TOT];
    const int t = threadIdx.x;
    const int img = blockIdx.x;
    const int l = t & 63, wave = t >> 6, half = l >> 5, lane31 = l & 31;

    float* xs = (float*)(lds + L_XS);
    signed char* h1 = (signed char*)(lds + L_H1);
    signed char* h2 = (signed char*)(lds + L_H2);
    u16*  h2u = (u16*)(lds + L_H2B);
    uint* h2w = (uint*)(lds + L_H2B);
    u16*  h3u = (u16*)(lds + L_H3);
    uint* h3  = (uint*)(lds + L_H3);
    uint (*red)[5] = (uint(*)[5])(lds + L_RED);
    float* lg = (float*)(lds + L_LG);

    // ---- load image ----
    {
        const float* xin = x + (size_t)img * 784;
        for (int i = t; i < 784; i += 256) xs[i] = xin[i];
    }
    __syncthreads();

    // ---- conv1: 2x2 spatial tile/thread (rows 2g,2g+1 x cols 2c,2c+1),
    // 169 active threads, window = 12 v2f pairs (24 VGPR), 18 pk_fma/oc
    // for 4 positions. Merged rare fp64 fallback.
    if (t < 169) {
        const float* wf = (const float*)wsu;   // uniform -> scalar loads
        const int g = t / 13, cc = (t - g * 13) * 2;
        const int y0 = 2 * g;
        // p[ky][c] = (xs[y0+ky][cc+c], xs[y0+ky+1][cc+c]), ky=0..2, c=0..3
        v2f p[3][4];
        #pragma unroll
        for (int ky = 0; ky < 3; ++ky)
            #pragma unroll
            for (int c = 0; c < 4; ++c) {
                v2f q;
                q.x = xs[(y0 + ky    )*28 + cc + c];
                q.y = xs[(y0 + ky + 1)*28 + cc + c];
                p[ky][c] = q;
            }
        uint m00 = 0, m10 = 0, m01 = 0, m11 = 0;
        for (int oc = 0; oc < 16; ++oc) {
            v2f sA = {0.f, 0.f}, sB = {0.f, 0.f};
            #pragma unroll
            for (int ky = 0; ky < 3; ++ky)
                #pragma unroll
                for (int kx = 0; kx < 3; ++kx) {
                    float w = wf[oc*9 + ky*3 + kx];
                    sA = p[ky][kx    ] * w + sA;   // v_pk_fma_f32
                    sB = p[ky][kx + 1] * w + sB;
                }
            // sA = (out[y0][cc], out[y0+1][cc]); sB = same at col cc+1
            bool b00 = (sA.x >= 0.f), b10 = (sA.y >= 0.f);
            bool b01 = (sB.x >= 0.f), b11 = (sB.y >= 0.f);
            // fp32 accum error bound ~2.9e-5 << 1e-4: outside the band the
            // fp32 sign equals the exact (fp64) sign.
            float mx = fmaxf(fmaxf(fabsf(sA.x), fabsf(sA.y)),
                             fmaxf(fabsf(sB.x), fabsf(sB.y)));
            if (__builtin_expect(mx < 1e-4f, 0)) {
                double rw[4][4];
                for (int c = 0; c < 4; ++c) {
                    rw[0][c] = (double)p[0][c].x;
                    rw[1][c] = (double)p[1][c].x;
                    rw[2][c] = (double)p[2][c].x;
                    rw[3][c] = (double)p[2][c].y;
                }
                double d00 = 0.0, d10 = 0.0, d01 = 0.0, d11 = 0.0;
                for (int k = 0; k < 9; ++k) {
                    int ky = k / 3, kx = k - ky*3;
                    double w = (double)wf[oc*9 + k];
                    d00 += w * rw[ky    ][kx    ];
                    d10 += w * rw[ky + 1][kx    ];
                    d01 += w * rw[ky    ][kx + 1];
                    d11 += w * rw[ky + 1][kx + 1];
                }
                b00 = (d00 >= 0.0); b10 = (d10 >= 0.0);
                b01 = (d01 >= 0.0); b11 = (d11 >= 0.0);
            }
            m00 |= (uint)b00 << oc;
            m10 |= (uint)b10 << oc;
            m01 |= (uint)b01 << oc;
            m11 |= (uint)b11 << oc;
        }
        *(v4i*)(h1 + ((y0    )*26 + cc    )*16) = expand16(m00);
        *(v4i*)(h1 + ((y0    )*26 + cc + 1)*16) = expand16(m01);
        *(v4i*)(h1 + ((y0 + 1)*26 + cc    )*16) = expand16(m10);
        *(v4i*)(h1 + ((y0 + 1)*26 + cc + 1)*16) = expand16(m11);
    }
    __syncthreads();

    // ---- conv2 via i8 MFMA, SWAPPED operands: D[oc][pos] ----
    {
        const v4i* w2bp = (const v4i*)(wsu + WS_W2B);
        v4i b2f[5];
        #pragma unroll
        for (int s = 0; s < 5; ++s) b2f[s] = w2bp[s*64 + l];
        for (int tile = wave; tile < 18; tile += 4) {
            const int mb = tile * 32;
            const int row = mb + lane31;
            const int y = row / 24, xx = row % 24;
            v16i acc = {0,0,0,0,0,0,0,0,0,0,0,0,0,0,0,0};
            #pragma unroll
            for (int s = 0; s < 5; ++s) {
                int tap = s*2 + half; if (tap > 8) tap = 8;  // W zeroed for tap 9
                int ky = tap / 3, kx = tap - ky*3;
                v4i b = *(const v4i*)(h1 + ((y+ky)*26 + xx+kx)*16);
                acc = __builtin_amdgcn_mfma_i32_32x32x32_i8(b2f[s], b, acc, 0, 0, 0);
            }
            uint mneg = 0;
            #pragma unroll
            for (int r = 0; r < 16; ++r)
                mneg |= (((uint)acc[r]) >> 31) << r;   // bit r = sign(oc(r,half))
            h2u[row*2 + half] = (u16)~mneg;
        }
    }
    __syncthreads();

    // ---- expand h2w -> h2 i8[2][576][16]: read-all -> barrier -> write-all
    // (h2 hi-half writes overlap the h2w gap, so buffer reads first) ----
    {
        uint wbuf[3];
        int np = 0;
        for (int p = t; p < 576; p += 256) wbuf[np++] = h2w[p];
        __syncthreads();
        np = 0;
        for (int p = t; p < 576; p += 256) {
            uint w = wbuf[np++];
            v4i lo, hi;
            lo[0] = expand4( w        & 0xFu);
            lo[1] = expand4((w >> 16) & 0xFu);
            lo[2] = expand4((w >>  4) & 0xFu);
            lo[3] = expand4((w >> 20) & 0xFu);
            hi[0] = expand4((w >>  8) & 0xFu);
            hi[1] = expand4((w >> 24) & 0xFu);
            hi[2] = expand4((w >> 12) & 0xFu);
            hi[3] = expand4((w >> 28) & 0xFu);
            *(v4i*)(h2 + p*16)        = lo;   // ic 0-15
            *(v4i*)(h2 + 9216 + p*16) = hi;   // ic 16-31
        }
    }
    __syncthreads();

    // ---- conv3 via i8 MFMA, SWAPPED operands: D[oc][pos] ----
    {
        const v4i* w3bp = (const v4i*)(wsu + WS_W3B);
        v4i b3f[9];
        #pragma unroll
        for (int s = 0; s < 9; ++s) b3f[s] = w3bp[s*64 + l];
        const signed char* h2h = h2 + half*9216;
        for (int tile = wave; tile < 16; tile += 4) {
            const int mb = tile * 32;
            int row = mb + lane31;
            int pr = (row < 484) ? row : 483;
            const int y = pr / 22, xx = pr % 22;
            v16i acc = {0,0,0,0,0,0,0,0,0,0,0,0,0,0,0,0};
            #pragma unroll
            for (int s = 0; s < 9; ++s) {
                const int ky = s / 3, kx = s - ky*3;
                v4i b = *(const v4i*)(h2h + ((y+ky)*24 + xx+kx)*16);
                acc = __builtin_amdgcn_mfma_i32_32x32x32_i8(b3f[s], b, acc, 0, 0, 0);
            }
            uint mneg = 0;
            #pragma unroll
            for (int r = 0; r < 16; ++r)
                mneg |= (((uint)acc[r]) >> 31) << r;
            if (row < 484) h3u[row*2 + half] = (u16)~mneg;
        }
    }
    __syncthreads();

    // ---- avgpool + FC as binary dot (permuted bits match wfc packing) ----
    uint acc5[5] = {0u, 0u, 0u, 0u, 0u};
    for (int p = t; p < 484; p += 256) {
        uint h = h3[p];
        const uint* wp = wsu + WS_FC + p;
        #pragma unroll
        for (int o = 0; o < 5; ++o)
            acc5[o] += (uint)__popc(h ^ wp[(2*o)*484])
                     + ((uint)__popc(h ^ wp[(2*o+1)*484]) << 16);
    }
    #pragma unroll
    for (int o = 0; o < 5; ++o) {
        uint v = acc5[o];
        v += __shfl_down(v, 32); v += __shfl_down(v, 16);
        v += __shfl_down(v, 8);  v += __shfl_down(v, 4);
        v += __shfl_down(v, 2);  v += __shfl_down(v, 1);
        acc5[o] = v;
    }
    if (l == 0) {
        #pragma unroll
        for (int o = 0; o < 5; ++o) red[wave][o] = acc5[o];
    }
    __syncthreads();
    if (t < 10) {
        uint S = 0;
        #pragma unroll
        for (int j = 0; j < 4; ++j) {
            uint w = red[j][t >> 1];
            S += (t & 1) ? (w >> 16) : (w & 0xFFFFu);
        }
        lg[t] = 0.25f * (float)(15488 - 2*(int)S) + bfc[t];
    }
    __syncthreads();
    if (t < 10) {
        float m = lg[0];
        #pragma unroll
        for (int o = 1; o < 10; ++o) m = fmaxf(m, lg[o]);
        float se = 0.f;
        #pragma unroll
        for (int o = 0; o < 10; ++o) se += expf(lg[o] - m);
        out[(size_t)img*10 + t] = lg[t] - m - logf(se);
    }
}

extern "C" void kernel_launch(void* const* d_in, const int* in_sizes, int n_in,
                              void* d_out, int out_size, void* d_ws, size_t ws_size,
                              hipStream_t stream)
{
    const float* x   = (const float*)d_in[0];
    const float* w1  = (const float*)d_in[1];
    const float* w2  = (const float*)d_in[2];
    const float* w3  = (const float*)d_in[3];
    const float* wfc = (const float*)d_in[4];
    const float* bfc = (const float*)d_in[5];
    float* out = (float*)d_out;
    uint* wsu  = (uint*)d_ws;

    const int B = in_sizes[0] / 784;   // 8192

    hipLaunchKernelGGL(pack_kernel, dim3(23), dim3(256), 0, stream,
                       w1, w2, w3, wfc, wsu);
    hipLaunchKernelGGL(binet_kernel, dim3(B), dim3(256), 0, stream,
                       x, wsu, bfc, out);
}

// Round 17
// 110.066 us; speedup vs baseline: 1.2713x; 1.1221x over previous
//
#include <hip/hip_runtime.h>
#include <cstdint>

typedef unsigned uint;
typedef unsigned short u16;
typedef int v4i  __attribute__((ext_vector_type(4)));
typedef int v16i __attribute__((ext_vector_type(16)));
typedef float v2f __attribute__((ext_vector_type(2)));

// d_ws word layout:
//   [0,144)       w1 signs as +-1.0f
//   [144,1424)    W2B: conv2 weight frags, f=s*64+l: oc=l&31, tap=2s+(l>>5), ic=e
//   [1424,3728)   W3B: conv3 weight frags, f=s*64+l: oc=l&31, tap=s, ic=(l>>5)*16+e
//   [3728,8568)   wfc packed to 22x22 grid, PERMUTED bit order (see bitpos)
static constexpr int WS_W2B = 144;
static constexpr int WS_W3B = 1424;
static constexpr int WS_FC  = 3728;

// LDS layout, 20368B (-> 20480 granule; target 8 blocks/CU).
// Region A [0,18432):
//   conv1:  xs f32[784] [0,3136) + h1 i8[676][16] [3136,13952)
//   conv2:  reads h1; writes h2w u16[576][2] into gap [13952,16256)
//   expand: reads h2w to 3 named regs, barrier, writes h2 i8[2][576][16]
//   FC:     red uint[4][5] at [0,80), lg float[10] at [80,120) (A dead)
// Region B [18432,20368): h3 uint[484] (conv3 out / FC in)
static constexpr int L_XS  = 0;
static constexpr int L_H1  = 3136;
static constexpr int L_H2  = 0;
static constexpr int L_H2B = 13952;
static constexpr int L_H3  = 18432;
static constexpr int L_RED = 0;
static constexpr int L_LG  = 80;
static constexpr int L_TOT = 20368;

// Permuted bit position for channel c in h2w/h3 words:
// lane-half h = c[2], reg r = (c&3) + 4*(c>>3); bitpos = 16h + r.
__device__ __host__ __forceinline__ int bitpos32(int c) {
    return (((c >> 2) & 1) << 4) + (c & 3) + ((c >> 3) << 2);
}

__global__ __launch_bounds__(256) void pack_kernel(
    const float* __restrict__ w1, const float* __restrict__ w2,
    const float* __restrict__ w3, const float* __restrict__ wfc,
    uint* __restrict__ wsu)
{
    int gid = blockIdx.x * 256 + threadIdx.x;
    if (gid < 144) {
        ((float*)wsu)[gid] = (w1[gid] >= 0.f) ? 1.f : -1.f;
    } else if (gid < 464) {
        // conv2 weight frag (A-operand): oc = l&31, tap = 2s+(l>>5), ic = e
        int f = gid - 144, s = f >> 6, l = f & 63;
        int oc = l & 31, tap = s * 2 + (l >> 5);
        uint w[4] = {0u, 0u, 0u, 0u};
        if (tap < 9) {
            for (int e = 0; e < 16; ++e) {
                uint b = (w2[(oc * 16 + e) * 9 + tap] >= 0.f) ? 0x01u : 0xFFu;
                w[e >> 2] |= b << (8 * (e & 3));
            }
        }
        for (int j = 0; j < 4; ++j) wsu[WS_W2B + f * 4 + j] = w[j];
    } else if (gid < 1040) {
        // conv3 weight frag (A-operand): oc = l&31, tap = s, ic = (l>>5)*16+e
        int f = gid - 464, s = f >> 6, l = f & 63;
        int oc = l & 31, icb = (l >> 5) * 16;
        uint w[4] = {0u, 0u, 0u, 0u};
        for (int e = 0; e < 16; ++e) {
            uint b = (w3[(oc * 32 + icb + e) * 9 + s] >= 0.f) ? 0x01u : 0xFFu;
            w[e >> 2] |= b << (8 * (e & 3));
        }
        for (int j = 0; j < 4; ++j) wsu[WS_W3B + f * 4 + j] = w[j];
    } else if (gid < 5880) {
        // FC weights, bit order matching conv3's per-lane mask build.
        int f = gid - 1040, o = f / 484, p = f % 484;
        int Y = p / 22, X = p % 22;
        const float* base = wfc + o * 3872 + (Y >> 1) * 11 + (X >> 1);
        uint bits = 0;
        for (int c = 0; c < 32; ++c)
            bits |= (base[c * 121] >= 0.f ? 1u : 0u) << bitpos32(c);
        wsu[WS_FC + f] = bits;
    }
}

// 4 sign bits -> 4 i8 bytes (bit=1 -> +1, bit=0 -> -1)
__device__ __forceinline__ int expand4(uint t) {
    return (int)~(((t * 0x00204081u) & 0x01010101u) * 0xFEu);
}
__device__ __forceinline__ v4i expand16(uint bits) {
    v4i r;
    r[0] = expand4(bits & 0xFu);
    r[1] = expand4((bits >> 4) & 0xFu);
    r[2] = expand4((bits >> 8) & 0xFu);
    r[3] = expand4((bits >> 12) & 0xFu);
    return r;
}
// Unpack one permuted h2w word into half-split h2 (lo at p, hi at 9216+p).
__device__ __forceinline__ void expand_store(signed char* h2, int p, uint w) {
    v4i lo, hi;
    lo[0] = expand4( w        & 0xFu);
    lo[1] = expand4((w >> 16) & 0xFu);
    lo[2] = expand4((w >>  4) & 0xFu);
    lo[3] = expand4((w >> 20) & 0xFu);
    hi[0] = expand4((w >>  8) & 0xFu);
    hi[1] = expand4((w >> 24) & 0xFu);
    hi[2] = expand4((w >> 12) & 0xFu);
    hi[3] = expand4((w >> 28) & 0xFu);
    *(v4i*)(h2 + p*16)        = lo;   // ic 0-15
    *(v4i*)(h2 + 9216 + p*16) = hi;   // ic 16-31
}

__global__ __launch_bounds__(256) void binet_kernel(
    const float* __restrict__ x, const uint* __restrict__ wsu,
    const float* __restrict__ bfc, float* __restrict__ out)
{
    __shared__ __align__(16) unsigned char lds[L_TOT];
    const int t = threadIdx.x;
    const int img = blockIdx.x;
    const int l = t & 63, wave = t >> 6, half = l >> 5, lane31 = l & 31;

    float* xs = (float*)(lds + L_XS);
    signed char* h1 = (signed char*)(lds + L_H1);
    signed char* h2 = (signed char*)(lds + L_H2);
    u16*  h2u = (u16*)(lds + L_H2B);
    uint* h2w = (uint*)(lds + L_H2B);
    u16*  h3u = (u16*)(lds + L_H3);
    uint* h3  = (uint*)(lds + L_H3);
    uint (*red)[5] = (uint(*)[5])(lds + L_RED);
    float* lg = (float*)(lds + L_LG);

    // ---- load image ----
    {
        const float* xin = x + (size_t)img * 784;
        for (int i = t; i < 784; i += 256) xs[i] = xin[i];
    }
    __syncthreads();

    // ---- conv1 (R12-proven): 3 rows/thread, pk-fma pair + scalar third;
    // merged rare fp64 fallback. Thread (g=t/26, xcol=t%26), rows 3g..3g+2.
    if (t < 234) {
        const float* wf = (const float*)wsu;   // uniform -> scalar loads
        const int g = t / 26, xcol = t - g * 26;
        const int y0 = 3 * g;
        float xv[5][3];
        #pragma unroll
        for (int r = 0; r < 5; ++r) {
            int rr = y0 + r; if (rr > 27) rr = 27;   // g=8 clamp (rows unused)
            #pragma unroll
            for (int c = 0; c < 3; ++c)
                xv[r][c] = xs[rr*28 + xcol + c];
        }
        v2f xp[9];
        #pragma unroll
        for (int ky = 0; ky < 3; ++ky)
            #pragma unroll
            for (int kx = 0; kx < 3; ++kx) {
                v2f p; p.x = xv[ky][kx]; p.y = xv[ky+1][kx];
                xp[ky*3+kx] = p;
            }
        uint m0 = 0, m1 = 0, m2 = 0;
        for (int oc = 0; oc < 16; ++oc) {
            v2f s01 = {0.f, 0.f};
            float s2 = 0.f;
            #pragma unroll
            for (int ky = 0; ky < 3; ++ky)
                #pragma unroll
                for (int kx = 0; kx < 3; ++kx) {
                    float w = wf[oc*9 + ky*3 + kx];
                    s01 = xp[ky*3+kx] * w + s01;          // v_pk_fma_f32
                    s2  = fmaf(xv[ky + 2][kx], w, s2);
                }
            float s0 = s01.x, s1 = s01.y;
            bool b0 = (s0 >= 0.f), b1 = (s1 >= 0.f), b2 = (s2 >= 0.f);
            // fp32 accum error bound ~2.9e-5 << 1e-4: outside the band the
            // fp32 sign equals the exact (fp64) sign.
            if (__builtin_expect((int)((fabsf(s0) < 1e-4f) |
                                       (fabsf(s1) < 1e-4f) |
                                       (fabsf(s2) < 1e-4f)), 0)) {
                double d0 = 0.0, d1 = 0.0, d2 = 0.0;
                for (int k = 0; k < 9; ++k) {
                    double w = (double)wf[oc*9 + k];
                    d0 += (double)xv[k/3    ][k%3] * w;
                    d1 += (double)xv[k/3 + 1][k%3] * w;
                    d2 += (double)xv[k/3 + 2][k%3] * w;
                }
                b0 = (d0 >= 0.0); b1 = (d1 >= 0.0); b2 = (d2 >= 0.0);
            }
            m0 |= (uint)b0 << oc;
            m1 |= (uint)b1 << oc;
            m2 |= (uint)b2 << oc;
        }
        *(v4i*)(h1 + ((y0    )*26 + xcol)*16) = expand16(m0);
        *(v4i*)(h1 + ((y0 + 1)*26 + xcol)*16) = expand16(m1);
        if (y0 + 2 <= 25)
            *(v4i*)(h1 + ((y0 + 2)*26 + xcol)*16) = expand16(m2);
    }
    __syncthreads();

    // ---- conv2 via i8 MFMA, SWAPPED operands: D[oc][pos] ----
    {
        const v4i* w2bp = (const v4i*)(wsu + WS_W2B);
        v4i b2f[5];
        #pragma unroll
        for (int s = 0; s < 5; ++s) b2f[s] = w2bp[s*64 + l];
        for (int tile = wave; tile < 18; tile += 4) {
            const int mb = tile * 32;
            const int row = mb + lane31;
            const int y = row / 24, xx = row % 24;
            v16i acc = {0,0,0,0,0,0,0,0,0,0,0,0,0,0,0,0};
            #pragma unroll
            for (int s = 0; s < 5; ++s) {
                int tap = s*2 + half; if (tap > 8) tap = 8;  // W zeroed for tap 9
                int ky = tap / 3, kx = tap - ky*3;
                v4i b = *(const v4i*)(h1 + ((y+ky)*26 + xx+kx)*16);
                acc = __builtin_amdgcn_mfma_i32_32x32x32_i8(b2f[s], b, acc, 0, 0, 0);
            }
            uint mneg = 0;
            #pragma unroll
            for (int r = 0; r < 16; ++r)
                mneg |= (((uint)acc[r]) >> 31) << r;   // bit r = sign(oc(r,half))
            h2u[row*2 + half] = (u16)~mneg;
        }
    }
    __syncthreads();

    // ---- expand h2w -> h2 i8[2][576][16]: 3 named regs -> barrier -> write
    // (h2 hi-half writes overlap the h2w gap; reads buffered first; no
    //  runtime-indexed array -> stays in VGPRs) ----
    {
        uint w0 = h2w[t];
        uint w1 = h2w[t + 256];
        uint w2 = (t < 64) ? h2w[t + 512] : 0u;
        __syncthreads();
        expand_store(h2, t, w0);
        expand_store(h2, t + 256, w1);
        if (t < 64) expand_store(h2, t + 512, w2);
    }
    __syncthreads();

    // ---- conv3 via i8 MFMA, SWAPPED operands: D[oc][pos] ----
    {
        const v4i* w3bp = (const v4i*)(wsu + WS_W3B);
        v4i b3f[9];
        #pragma unroll
        for (int s = 0; s < 9; ++s) b3f[s] = w3bp[s*64 + l];
        const signed char* h2h = h2 + half*9216;
        for (int tile = wave; tile < 16; tile += 4) {
            const int mb = tile * 32;
            int row = mb + lane31;
            int pr = (row < 484) ? row : 483;
            const int y = pr / 22, xx = pr % 22;
            v16i acc = {0,0,0,0,0,0,0,0,0,0,0,0,0,0,0,0};
            #pragma unroll
            for (int s = 0; s < 9; ++s) {
                const int ky = s / 3, kx = s - ky*3;
                v4i b = *(const v4i*)(h2h + ((y+ky)*24 + xx+kx)*16);
                acc = __builtin_amdgcn_mfma_i32_32x32x32_i8(b3f[s], b, acc, 0, 0, 0);
            }
            uint mneg = 0;
            #pragma unroll
            for (int r = 0; r < 16; ++r)
                mneg |= (((uint)acc[r]) >> 31) << r;
            if (row < 484) h3u[row*2 + half] = (u16)~mneg;
        }
    }
    __syncthreads();

    // ---- avgpool + FC as binary dot (permuted bits match wfc packing) ----
    uint acc5[5] = {0u, 0u, 0u, 0u, 0u};
    for (int p = t; p < 484; p += 256) {
        uint h = h3[p];
        const uint* wp = wsu + WS_FC + p;
        #pragma unroll
        for (int o = 0; o < 5; ++o)
            acc5[o] += (uint)__popc(h ^ wp[(2*o)*484])
                     + ((uint)__popc(h ^ wp[(2*o+1)*484]) << 16);
    }
    #pragma unroll
    for (int o = 0; o < 5; ++o) {
        uint v = acc5[o];
        v += __shfl_down(v, 32); v += __shfl_down(v, 16);
        v += __shfl_down(v, 8);  v += __shfl_down(v, 4);
        v += __shfl_down(v, 2);  v += __shfl_down(v, 1);
        acc5[o] = v;
    }
    if (l == 0) {
        #pragma unroll
        for (int o = 0; o < 5; ++o) red[wave][o] = acc5[o];
    }
    __syncthreads();
    if (t < 10) {
        uint S = 0;
        #pragma unroll
        for (int j = 0; j < 4; ++j) {
            uint w = red[j][t >> 1];
            S += (t & 1) ? (w >> 16) : (w & 0xFFFFu);
        }
        lg[t] = 0.25f * (float)(15488 - 2*(int)S) + bfc[t];
    }
    __syncthreads();
    if (t < 10) {
        float m = lg[0];
        #pragma unroll
        for (int o = 1; o < 10; ++o) m = fmaxf(m, lg[o]);
        float se = 0.f;
        #pragma unroll
        for (int o = 0; o < 10; ++o) se += expf(lg[o] - m);
        out[(size_t)img*10 + t] = lg[t] - m - logf(se);
    }
}

extern "C" void kernel_launch(void* const* d_in, const int* in_sizes, int n_in,
                              void* d_out, int out_size, void* d_ws, size_t ws_size,
                              hipStream_t stream)
{
    const float* x   = (const float*)d_in[0];
    const float* w1  = (const float*)d_in[1];
    const float* w2  = (const float*)d_in[2];
    const float* w3  = (const float*)d_in[3];
    const float* wfc = (const float*)d_in[4];
    const float* bfc = (const float*)d_in[5];
    float* out = (float*)d_out;
    uint* wsu  = (uint*)d_ws;

    const int B = in_sizes[0] / 784;   // 8192

    hipLaunchKernelGGL(pack_kernel, dim3(23), dim3(256), 0, stream,
                       w1, w2, w3, wfc, wsu);
    hipLaunchKernelGGL(binet_kernel, dim3(B), dim3(256), 0, stream,
                       x, wsu, bfc, out);
}